// Round 3
// baseline (1977.037 us; speedup 1.0000x reference)
//
#include <hip/hip_runtime.h>
#include <stdint.h>

typedef unsigned int u32;
typedef unsigned long long u64;

// Problem constants
#define NQ    8192      // 8*32*32 query vectors
#define DIMK  256       // e_dim
#define NE    16384     // n_e codebook entries
#define CSTR  1024      // stride of c within z[b] (32*32)
#define BSTR  262144    // stride of b within z (256*1024)

// GEMM tiling
#define BN 128
#define BM 128
#define BK 32
#define MC 2048
#define LSTR 132

#define SLOTS  32
#define MARGIN 1.5e-4f  // >= 2*ulp(512) quantized-tie window, 2.5x headroom

// ws layout (bytes)
#define WS_EE_OFF    256        // float ee[16384]   (numpy-bitwise ||e||^2)
#define WS_ZZ_OFF    65792      // float zz[8192]    (numpy-bitwise ||z||^2)
#define WS_KEY_OFF   98560      // u64 keys[8192]
#define WS_CNT_OFF   164096     // u32 cnt[8192]
#define WS_FIDX_OFF  196864     // int final_idx[8192]
#define WS_CAND_OFF  229632     // u32 cand[8192*SLOTS] (1 MB)

// ---- numpy pairwise sum of squares, bitwise replica (n=256) ----
// numpy: n=256 -> two 128-halves; each: 8 accumulators stride 8;
// combine ((r0+r1)+(r2+r3))+((r4+r5)+(r6+r7)); halves added.
__device__ __forceinline__ float np_pairwise_sq(const float* __restrict__ a, int stride) {
    float hs[2];
#pragma unroll
    for (int h = 0; h < 2; ++h) {
        const float* p = a + (size_t)(h * 128) * stride;
        float r[8];
#pragma unroll
        for (int j = 0; j < 8; ++j) {
            float v = p[(size_t)j * stride];
            r[j] = __fmul_rn(v, v);
        }
        for (int i = 8; i < 128; i += 8) {
#pragma unroll
            for (int j = 0; j < 8; ++j) {
                float v = p[(size_t)(i + j) * stride];
                r[j] = __fadd_rn(r[j], __fmul_rn(v, v));
            }
        }
        hs[h] = __fadd_rn(__fadd_rn(__fadd_rn(r[0], r[1]), __fadd_rn(r[2], r[3])),
                          __fadd_rn(__fadd_rn(r[4], r[5]), __fadd_rn(r[6], r[7])));
    }
    return __fadd_rn(hs[0], hs[1]);
}

// ---- numpy einsum inner product replica: SSE baseline (W=4, no FMA) ----
// single 4-lane accumulator, add(mul) chained stride-4; hadd tree (l0+l1)+(l2+l3)
__device__ __forceinline__ float np_einsum_dot(const float* __restrict__ zr, int zstride,
                                               const float* __restrict__ er) {
    float a0 = 0.0f, a1 = 0.0f, a2 = 0.0f, a3 = 0.0f;
    for (int s = 0; s < 64; ++s) {
        const int k = s * 4;
        a0 = __fadd_rn(a0, __fmul_rn(zr[(size_t)(k + 0) * zstride], er[k + 0]));
        a1 = __fadd_rn(a1, __fmul_rn(zr[(size_t)(k + 1) * zstride], er[k + 1]));
        a2 = __fadd_rn(a2, __fmul_rn(zr[(size_t)(k + 2) * zstride], er[k + 2]));
        a3 = __fadd_rn(a3, __fmul_rn(zr[(size_t)(k + 3) * zstride], er[k + 3]));
    }
    return __fadd_rn(__fadd_rn(a0, a1), __fadd_rn(a2, a3));
}

__global__ __launch_bounds__(256)
void k_prep(const float* __restrict__ z, const float* __restrict__ E,
            float* __restrict__ ee, float* __restrict__ zz,
            u64* __restrict__ keys, u32* __restrict__ cnt, float* __restrict__ acc) {
    const int j = blockIdx.x * 256 + threadIdx.x;
    if (j == 0) *acc = 0.0f;
    if (j < NQ) { keys[j] = 0xFFFFFFFFFFFFFFFFULL; cnt[j] = 0u; }
    ee[j] = np_pairwise_sq(E + (size_t)j * DIMK, 1);
    if (j < NQ) {
        const int b = j >> 10, hw = j & 1023;
        zz[j] = np_pairwise_sq(z + (size_t)b * BSTR + hw, CSTR);
    }
}

// MODE 0: per-row argmin of (ee[j] - 2*z.e) -> u64 atomicMin keys
// MODE 1: append all j with v <= unmap(keys)+MARGIN to cand list
template <int MODE>
__global__ __launch_bounds__(256)
void k_gemm(const float* __restrict__ z, const float* __restrict__ E,
            const float* __restrict__ be,
            u64* __restrict__ keys, u32* __restrict__ cnt,
            u32* __restrict__ cand) {
    __shared__ float Al[BK * LSTR];
    __shared__ float Bl[BK * LSTR];

    const int t   = threadIdx.x;
    const int bid = blockIdx.x;
    const int by  = bid >> 3;
    const int mc  = bid & 7;
    const int n0  = by * BN;
    const int b   = n0 >> 10;
    const int hw0 = n0 & 1023;
    const float* zbase = z + (size_t)b * BSTR + hw0;
    const int j0c = mc * MC;

    const int tx = t & 15;
    const int ty = t >> 4;

    float minv[8];
    int   mini[8];
    float limit[8];
#pragma unroll
    for (int i = 0; i < 8; ++i) { minv[i] = 3.402823e38f; mini[i] = 0; }
    if (MODE == 1) {
#pragma unroll
        for (int i = 0; i < 8; ++i) {
            u32 u = (u32)(keys[n0 + ty * 8 + i] >> 32);
            u = (u & 0x80000000u) ? (u ^ 0x80000000u) : ~u;
            limit[i] = __uint_as_float(u) + MARGIN;
        }
    }

    for (int jt = 0; jt < MC / BM; ++jt) {
        const int j0 = j0c + jt * BM;
        float c[8][8];
#pragma unroll
        for (int i = 0; i < 8; ++i)
#pragma unroll
            for (int jj = 0; jj < 8; ++jj) c[i][jj] = 0.0f;

        for (int kt = 0; kt < DIMK; kt += BK) {
            float4 av[4];
            {
                const int c4  = t & 31;
                const int kk0 = t >> 5;
#pragma unroll
                for (int i = 0; i < 4; ++i) {
                    int kk = kk0 + i * 8;
                    av[i] = *(const float4*)(zbase + (size_t)(kt + kk) * CSTR + c4 * 4);
                }
            }
            float4 bv[4];
            {
                const int f4 = t & 7;
                const int r0 = t >> 3;
#pragma unroll
                for (int i = 0; i < 4; ++i) {
                    int r = r0 + i * 32;
                    bv[i] = *(const float4*)(E + (size_t)(j0 + r) * DIMK + kt + f4 * 4);
                }
            }
            __syncthreads();
            {
                const int c4  = t & 31;
                const int kk0 = t >> 5;
#pragma unroll
                for (int i = 0; i < 4; ++i) {
                    int kk = kk0 + i * 8;
                    *(float4*)(&Al[kk * LSTR + c4 * 4]) = av[i];
                }
            }
            {
                const int f4 = t & 7;
                const int r0 = t >> 3;
#pragma unroll
                for (int i = 0; i < 4; ++i) {
                    int r = r0 + i * 32;
                    Bl[(f4 * 4 + 0) * LSTR + r] = bv[i].x;
                    Bl[(f4 * 4 + 1) * LSTR + r] = bv[i].y;
                    Bl[(f4 * 4 + 2) * LSTR + r] = bv[i].z;
                    Bl[(f4 * 4 + 3) * LSTR + r] = bv[i].w;
                }
            }
            __syncthreads();

#pragma unroll
            for (int kk = 0; kk < BK; ++kk) {
                float4 a0 = *(const float4*)(&Al[kk * LSTR + ty * 8]);
                float4 a1 = *(const float4*)(&Al[kk * LSTR + ty * 8 + 4]);
                float4 b0 = *(const float4*)(&Bl[kk * LSTR + tx * 8]);
                float4 b1 = *(const float4*)(&Bl[kk * LSTR + tx * 8 + 4]);
                float aa[8] = {a0.x, a0.y, a0.z, a0.w, a1.x, a1.y, a1.z, a1.w};
                float bb[8] = {b0.x, b0.y, b0.z, b0.w, b1.x, b1.y, b1.z, b1.w};
#pragma unroll
                for (int i = 0; i < 8; ++i)
#pragma unroll
                    for (int jj = 0; jj < 8; ++jj)
                        c[i][jj] = fmaf(aa[i], bb[jj], c[i][jj]);
            }
            __syncthreads();
        }

        float4 q0 = *(const float4*)(be + j0 + tx * 8);
        float4 q1 = *(const float4*)(be + j0 + tx * 8 + 4);
        float bvals[8] = {q0.x, q0.y, q0.z, q0.w, q1.x, q1.y, q1.z, q1.w};
#pragma unroll
        for (int jj = 0; jj < 8; ++jj) {
            const float bj = bvals[jj];
            const int   jg = j0 + tx * 8 + jj;
#pragma unroll
            for (int i = 0; i < 8; ++i) {
                float v = bj - 2.0f * c[i][jj];
                if (MODE == 0) {
                    if (v < minv[i]) { minv[i] = v; mini[i] = jg; }
                } else {
                    if (v <= limit[i]) {
                        const int row = n0 + ty * 8 + i;
                        u32 p = atomicAdd(&cnt[row], 1u);
                        if (p < SLOTS) cand[(size_t)row * SLOTS + p] = (u32)jg;
                    }
                }
            }
        }
    }

    if (MODE == 0) {
        __syncthreads();
        float* rv = Al;
        int*   ri = (int*)Bl;
#pragma unroll
        for (int i = 0; i < 8; ++i) {
            rv[(ty * 8 + i) * 16 + tx] = minv[i];
            ri[(ty * 8 + i) * 16 + tx] = mini[i];
        }
        __syncthreads();
        if (t < BN) {
            float bestv = 3.402823e38f;
            int   besti = 0x7FFFFFFF;
#pragma unroll
            for (int x = 0; x < 16; ++x) {
                float v  = rv[t * 16 + x];
                int   ix = ri[t * 16 + x];
                if (v < bestv || (v == bestv && ix < besti)) { bestv = v; besti = ix; }
            }
            u32 u = __float_as_uint(bestv);
            u = (u & 0x80000000u) ? ~u : (u | 0x80000000u);
            u64 key = ((u64)u << 32) | (u32)besti;
            atomicMin(&keys[n0 + t], key);
        }
    }
}

// numpy-bitwise rescore: d = fl(fl(zz+ee) - 2*ze_np), argmin with first-index-wins
__global__ __launch_bounds__(64)
void k_rescore(const float* __restrict__ z, const float* __restrict__ E,
               const float* __restrict__ zz, const float* __restrict__ ee,
               const u64* __restrict__ keys, const u32* __restrict__ cnt,
               const u32* __restrict__ cand,
               int* __restrict__ final_idx, float* __restrict__ out_idx) {
    const int q = blockIdx.x;
    const int t = threadIdx.x;
    const int b  = q >> 10;
    const int hw = q & 1023;
    const u32 n = min(cnt[q], (u32)SLOTS);

    int j = -1;
    if (t == 0)            j = (int)(keys[q] & 0xFFFFFFFFULL);  // phase-1 best (always valid)
    else if ((u32)(t - 1) < n) j = (int)cand[(size_t)q * SLOTS + (t - 1)];

    u64 key = 0xFFFFFFFFFFFFFFFFULL;
    if (j >= 0) {
        const float ze = np_einsum_dot(z + (size_t)b * BSTR + hw, CSTR, E + (size_t)j * DIMK);
        const float t1 = __fadd_rn(zz[q], ee[j]);
        const float d  = __fsub_rn(t1, __fmul_rn(2.0f, ze));
        u32 u = __float_as_uint(d);
        u = (u & 0x80000000u) ? ~u : (u | 0x80000000u);
        key = ((u64)u << 32) | (u32)j;   // min key == min d, ties -> lowest j
    }
#pragma unroll
    for (int off = 32; off > 0; off >>= 1) {
        u64 o = __shfl_down(key, off, 64);
        if (o < key) key = o;
    }
    if (t == 0) {
        const int bj = (int)(key & 0xFFFFFFFFULL);
        final_idx[q] = bj;
        out_idx[q] = (float)bj;
    }
}

__global__ __launch_bounds__(256)
void k_finalize(const float* __restrict__ z, const float* __restrict__ E,
                const int* __restrict__ final_idx,
                float* __restrict__ out0, float* __restrict__ acc) {
    __shared__ float red[256];
    const int t = threadIdx.x;
    const int q = blockIdx.x * 256 + t;
    const int idx = final_idx[q];
    const int b  = q >> 10;
    const int hw = q & 1023;
    const float* zb = z + (size_t)b * BSTR + hw;
    float*       ob = out0 + (size_t)b * BSTR + hw;
    const float* e  = E + (size_t)idx * DIMK;
    float ls = 0.0f;
    for (int c0 = 0; c0 < DIMK; ++c0) {
        float ev = e[c0];
        float zv = zb[(size_t)c0 * CSTR];
        float d  = ev - zv;
        ls = fmaf(d, d, ls);
        ob[(size_t)c0 * CSTR] = ev;
    }
    red[t] = ls;
    __syncthreads();
    for (int s = 128; s > 0; s >>= 1) {
        if (t < s) red[t] += red[t + s];
        __syncthreads();
    }
    if (t == 0) atomicAdd(acc, red[0]);
}

__global__ void k_loss(const float* __restrict__ acc, float* __restrict__ out_loss) {
    *out_loss = 1.25f * (*acc) * (1.0f / 2097152.0f);
}

extern "C" void kernel_launch(void* const* d_in, const int* in_sizes, int n_in,
                              void* d_out, int out_size, void* d_ws, size_t ws_size,
                              hipStream_t stream) {
    const float* z = (const float*)d_in[0];   // [8,256,32,32] fp32
    const float* E = (const float*)d_in[1];   // [16384,256] fp32

    float* out0     = (float*)d_out;
    float* out_loss = (float*)d_out + 2097152;
    float* out_idx  = (float*)d_out + 2097153;

    float* acc  = (float*)d_ws;
    float* ee   = (float*)((char*)d_ws + WS_EE_OFF);
    float* zz   = (float*)((char*)d_ws + WS_ZZ_OFF);
    u64*   keys = (u64*)  ((char*)d_ws + WS_KEY_OFF);
    u32*   cnt  = (u32*)  ((char*)d_ws + WS_CNT_OFF);
    int*   fidx = (int*)  ((char*)d_ws + WS_FIDX_OFF);
    u32*   cand = (u32*)  ((char*)d_ws + WS_CAND_OFF);

    k_prep<<<NE / 256, 256, 0, stream>>>(z, E, ee, zz, keys, cnt, acc);
    k_gemm<0><<<(NQ / BN) * (NE / MC), 256, 0, stream>>>(z, E, ee, keys, cnt, cand);
    k_gemm<1><<<(NQ / BN) * (NE / MC), 256, 0, stream>>>(z, E, ee, keys, cnt, cand);
    k_rescore<<<NQ, 64, 0, stream>>>(z, E, zz, ee, keys, cnt, cand, fidx, out_idx);
    k_finalize<<<NQ / 256, 256, 0, stream>>>(z, E, fidx, out0, acc);
    k_loss<<<1, 1, 0, stream>>>(acc, out_loss);
}

// Round 4
// 512.700 us; speedup vs baseline: 3.8561x; 3.8561x over previous
//
#include <hip/hip_runtime.h>
#include <stdint.h>

typedef unsigned int u32;
typedef unsigned long long u64;
typedef unsigned short ushort_t;

typedef short bf16x8 __attribute__((ext_vector_type(8)));
typedef float f32x4  __attribute__((ext_vector_type(4)));

// Problem constants
#define NQ    8192
#define DIMK  256
#define NE    16384
#define CSTR  1024
#define BSTR  262144

// MFMA filter tiling
#define BR 128          // query rows per block
#define BC 128          // code cols per block
#define BK 64           // k per staging tile (4 tiles of 64 = 256)
#define LS 72           // LDS row stride in bf16 units (144 B, 16B-aligned, 2-way banks)

#define SLOTS 96
#define CMARG 2.5e-4f   // covers np tie window (8e-5) + 2x bf16-GEMM error

// ws layout (bytes)
#define WS_EE_OFF    256        // float ee[16384]
#define WS_ZZ_OFF    65792      // float zz[8192]
#define WS_GMIN_OFF  98560      // u32 gmin[8192]
#define WS_CNT_OFF   131328     // u32 cnt[8192]
#define WS_FIDX_OFF  164096     // int fidx[8192]
#define WS_ZB_OFF    196864     // ushort zb16[8192*256]  (4 MB)
#define WS_CAND_OFF  4391168    // u64 cand[8192*96]      (6.3 MB) -> end ~10.2 MB

__device__ __forceinline__ u32 fmap(float f) {
    union { float f; u32 u; } x; x.f = f;
    return (x.u & 0x80000000u) ? ~x.u : (x.u | 0x80000000u);
}
__device__ __forceinline__ float funmap(u32 u) {
    union { float f; u32 u; } x;
    x.u = (u & 0x80000000u) ? (u ^ 0x80000000u) : ~u;
    return x.f;
}
__device__ __forceinline__ ushort_t f2bf(float f) {   // RNE, matches HW cvt for normals
    union { float f; u32 u; } x; x.f = f;
    u32 r = x.u + 0x7FFFu + ((x.u >> 16) & 1u);
    return (ushort_t)(r >> 16);
}

// ---- numpy pairwise sum of squares, bitwise replica (n=256) ----
__device__ __forceinline__ float np_pairwise_sq(const float* __restrict__ a, int stride) {
    float hs[2];
#pragma unroll
    for (int h = 0; h < 2; ++h) {
        const float* p = a + (size_t)(h * 128) * stride;
        float r[8];
#pragma unroll
        for (int j = 0; j < 8; ++j) { float v = p[(size_t)j * stride]; r[j] = __fmul_rn(v, v); }
        for (int i = 8; i < 128; i += 8) {
#pragma unroll
            for (int j = 0; j < 8; ++j) {
                float v = p[(size_t)(i + j) * stride];
                r[j] = __fadd_rn(r[j], __fmul_rn(v, v));
            }
        }
        hs[h] = __fadd_rn(__fadd_rn(__fadd_rn(r[0], r[1]), __fadd_rn(r[2], r[3])),
                          __fadd_rn(__fadd_rn(r[4], r[5]), __fadd_rn(r[6], r[7])));
    }
    return __fadd_rn(hs[0], hs[1]);
}

// ---- numpy einsum dot replica: SSE baseline (W=4, no FMA) — validated round 3 ----
__device__ __forceinline__ float np_einsum_dot(const float* __restrict__ zr, int zstride,
                                               const float* __restrict__ er) {
    float a0 = 0.0f, a1 = 0.0f, a2 = 0.0f, a3 = 0.0f;
    for (int s = 0; s < 64; ++s) {
        const int k = s * 4;
        a0 = __fadd_rn(a0, __fmul_rn(zr[(size_t)(k + 0) * zstride], er[k + 0]));
        a1 = __fadd_rn(a1, __fmul_rn(zr[(size_t)(k + 1) * zstride], er[k + 1]));
        a2 = __fadd_rn(a2, __fmul_rn(zr[(size_t)(k + 2) * zstride], er[k + 2]));
        a3 = __fadd_rn(a3, __fmul_rn(zr[(size_t)(k + 3) * zstride], er[k + 3]));
    }
    return __fadd_rn(__fadd_rn(a0, a1), __fadd_rn(a2, a3));
}

__global__ __launch_bounds__(256)
void k_prep(const float* __restrict__ z, const float* __restrict__ E,
            float* __restrict__ ee, float* __restrict__ zz,
            u32* __restrict__ gmin, u32* __restrict__ cnt, float* __restrict__ acc) {
    const int j = blockIdx.x * 256 + threadIdx.x;
    if (j == 0) *acc = 0.0f;
    if (j < NQ) {
        gmin[j] = 0xFFFFFFFFu;
        cnt[j] = 0u;
        const int b = j >> 10, hw = j & 1023;
        zz[j] = np_pairwise_sq(z + (size_t)b * BSTR + hw, CSTR);
    }
    ee[j] = np_pairwise_sq(E + (size_t)j * DIMK, 1);
}

// transpose-convert z [b][c][hw] fp32 -> zb16 [b*1024+hw][c] bf16
__global__ __launch_bounds__(256)
void k_zt(const float* __restrict__ z, ushort_t* __restrict__ zb16) {
    __shared__ float Lf[64][65];
    const int t   = threadIdx.x;
    const int bid = blockIdx.x;          // 8 b * 4 ct * 16 ht = 512
    const int b   = bid >> 6;
    const int ct  = (bid >> 4) & 3;
    const int ht  = bid & 15;
    const int c0  = ct * 64, hw0 = ht * 64;
#pragma unroll
    for (int i = 0; i < 16; ++i) {
        const int c_l = i * 4 + (t >> 6);
        const int hw_l = t & 63;
        Lf[c_l][hw_l] = z[(size_t)b * BSTR + (size_t)(c0 + c_l) * CSTR + hw0 + hw_l];
    }
    __syncthreads();
#pragma unroll
    for (int i = 0; i < 16; ++i) {
        const int hw_l = i * 4 + (t >> 6);
        const int c_l = t & 63;
        zb16[(size_t)(b * 1024 + hw0 + hw_l) * DIMK + c0 + c_l] = f2bf(Lf[c_l][hw_l]);
    }
}

// bf16 MFMA distance filter: v = ee[col] - 2 * (z . e), fused row-min + margin-collect
__global__ __launch_bounds__(256, 3)
void k_mfma_filter(const ushort_t* __restrict__ zb16, const float* __restrict__ E,
                   const float* __restrict__ ee,
                   u32* __restrict__ gmin, u32* __restrict__ cnt, u64* __restrict__ cand) {
    __shared__ ushort_t Al[BR * LS];
    __shared__ ushort_t Bl[BC * LS];
    __shared__ u32 rowmin[BR];

    const int t    = threadIdx.x;
    const int bid  = blockIdx.x;             // 64 rowblk x 128 colblk; row fastest
    const int q0   = (bid & 63) * BR;
    const int c0   = (bid >> 6) * BC;
    const int wave = t >> 6;
    const int lane = t & 63;
    const int quad = lane >> 4;
    const int l15  = lane & 15;
    const int wr   = (wave >> 1) * 64;       // wave's row offset in tile
    const int wc   = (wave & 1) * 64;        // wave's col offset in tile

    if (t < BR) rowmin[t] = 0xFFFFFFFFu;

    f32x4 acc[4][4];
#pragma unroll
    for (int fi = 0; fi < 4; ++fi)
#pragma unroll
        for (int fj = 0; fj < 4; ++fj)
#pragma unroll
            for (int r = 0; r < 4; ++r) acc[fi][fj][r] = 0.0f;

    const int srow  = t >> 1;                // staging row (0..127)
    const int shalf = (t & 1) * 32;          // 32 bf16 / 32 float half

    for (int kt = 0; kt < 4; ++kt) {
        // global loads into regs
        uint4 areg[4];
        {
            const ushort_t* gA = zb16 + (size_t)(q0 + srow) * DIMK + kt * BK + shalf;
#pragma unroll
            for (int i = 0; i < 4; ++i) areg[i] = *(const uint4*)(gA + i * 8);
        }
        ushort_t h[32];
        {
            const float* gB = E + (size_t)(c0 + srow) * DIMK + kt * BK + shalf;
#pragma unroll
            for (int i = 0; i < 8; ++i) {
                float4 f = *(const float4*)(gB + i * 4);
                h[i * 4 + 0] = f2bf(f.x); h[i * 4 + 1] = f2bf(f.y);
                h[i * 4 + 2] = f2bf(f.z); h[i * 4 + 3] = f2bf(f.w);
            }
        }
        __syncthreads();   // previous tile's fragment reads complete
        {
            ushort_t* dA = &Al[srow * LS + shalf];
#pragma unroll
            for (int i = 0; i < 4; ++i) *(uint4*)(dA + i * 8) = areg[i];
            ushort_t* dB = &Bl[srow * LS + shalf];
#pragma unroll
            for (int i = 0; i < 4; ++i) *(uint4*)(dB + i * 8) = *(const uint4*)(&h[i * 8]);
        }
        __syncthreads();

#pragma unroll
        for (int ks = 0; ks < 2; ++ks) {
            const int kofs = ks * 32 + quad * 8;
            bf16x8 af[4], bf[4];
#pragma unroll
            for (int fi = 0; fi < 4; ++fi)
                af[fi] = *(const bf16x8*)(&Al[(wr + fi * 16 + l15) * LS + kofs]);
#pragma unroll
            for (int fj = 0; fj < 4; ++fj)
                bf[fj] = *(const bf16x8*)(&Bl[(wc + fj * 16 + l15) * LS + kofs]);
#pragma unroll
            for (int fi = 0; fi < 4; ++fi)
#pragma unroll
                for (int fj = 0; fj < 4; ++fj)
                    acc[fi][fj] = __builtin_amdgcn_mfma_f32_16x16x32_bf16(
                        af[fi], bf[fj], acc[fi][fj], 0, 0, 0);
        }
        __syncthreads();
    }

    // epilogue: v = ee[col] - 2*dot ; fused row-min + collect
    float eev[4];
#pragma unroll
    for (int fj = 0; fj < 4; ++fj) eev[fj] = ee[c0 + wc + fj * 16 + l15];

    float vmin[4][4];
#pragma unroll
    for (int fi = 0; fi < 4; ++fi)
#pragma unroll
        for (int r = 0; r < 4; ++r) {
            float m = 3.402823e38f;
#pragma unroll
            for (int fj = 0; fj < 4; ++fj)
                m = fminf(m, eev[fj] - 2.0f * acc[fi][fj][r]);
#pragma unroll
            for (int off = 1; off < 16; off <<= 1)
                m = fminf(m, __shfl_xor(m, off, 16));
            vmin[fi][r] = m;
        }
    if (l15 == 0) {
#pragma unroll
        for (int fi = 0; fi < 4; ++fi)
#pragma unroll
            for (int r = 0; r < 4; ++r)
                atomicMin(&rowmin[wr + fi * 16 + quad * 4 + r], fmap(vmin[fi][r]));
    }
    __syncthreads();
    if (t < BR) {
        u32 lv = rowmin[t];
        u32 old = atomicMin(&gmin[q0 + t], lv);
        rowmin[t] = (old < lv) ? old : lv;
    }
    __syncthreads();

#pragma unroll
    for (int fi = 0; fi < 4; ++fi)
#pragma unroll
        for (int r = 0; r < 4; ++r) {
            const int rg = wr + fi * 16 + quad * 4 + r;
            const float thr = funmap(rowmin[rg]) + CMARG;
#pragma unroll
            for (int fj = 0; fj < 4; ++fj) {
                const float v = eev[fj] - 2.0f * acc[fi][fj][r];
                if (v <= thr) {
                    const int row = q0 + rg;
                    u32 p = atomicAdd(&cnt[row], 1u);
                    if (p < SLOTS)
                        cand[(size_t)row * SLOTS + p] =
                            ((u64)fmap(v) << 32) | (u32)(c0 + wc + fj * 16 + l15);
                }
            }
        }
}

// numpy-bitwise rescore over collected candidates
__global__ __launch_bounds__(64)
void k_rescore(const float* __restrict__ z, const float* __restrict__ E,
               const float* __restrict__ zz, const float* __restrict__ ee,
               const u32* __restrict__ cnt, const u64* __restrict__ cand,
               int* __restrict__ fidx, float* __restrict__ out_idx) {
    const int q = blockIdx.x;
    const int t = threadIdx.x;
    const int b  = q >> 10;
    const int hw = q & 1023;
    const u32 n = min(cnt[q], (u32)SLOTS);

    u64 c1 = (u32)t < n        ? cand[(size_t)q * SLOTS + t]      : 0xFFFFFFFFFFFFFFFFULL;
    u64 c2 = (u32)(t + 64) < n ? cand[(size_t)q * SLOTS + t + 64] : 0xFFFFFFFFFFFFFFFFULL;

    // wave-min of stored (bf16-GEMM) values
    u32 mv = (u32)(c1 >> 32);
    { u32 m2 = (u32)(c2 >> 32); if (m2 < mv) mv = m2; }
#pragma unroll
    for (int off = 1; off < 64; off <<= 1) {
        u32 o = __shfl_xor(mv, off, 64);
        if (o < mv) mv = o;
    }
    const float thr = funmap(mv) + CMARG;

    u64 best = 0xFFFFFFFFFFFFFFFFULL;
#pragma unroll
    for (int s = 0; s < 2; ++s) {
        const u64 c = s ? c2 : c1;
        if (c != 0xFFFFFFFFFFFFFFFFULL && funmap((u32)(c >> 32)) <= thr) {
            const int j = (int)(c & 0xFFFFFFFFULL);
            const float ze = np_einsum_dot(z + (size_t)b * BSTR + hw, CSTR, E + (size_t)j * DIMK);
            const float t1 = __fadd_rn(zz[q], ee[j]);
            const float d  = __fsub_rn(t1, __fmul_rn(2.0f, ze));
            u64 key = ((u64)fmap(d) << 32) | (u32)j;   // ties -> lowest j
            if (key < best) best = key;
        }
    }
#pragma unroll
    for (int off = 1; off < 64; off <<= 1) {
        u64 o = __shfl_xor(best, off, 64);
        if (o < best) best = o;
    }
    if (t == 0) {
        const int bj = (int)(best & 0xFFFFFFFFULL);
        fidx[q] = bj;
        out_idx[q] = (float)bj;
    }
}

__global__ __launch_bounds__(256)
void k_finalize(const float* __restrict__ z, const float* __restrict__ E,
                const int* __restrict__ fidx,
                float* __restrict__ out0, float* __restrict__ acc) {
    __shared__ float red[256];
    const int t = threadIdx.x;
    const int q = blockIdx.x * 256 + t;
    const int idx = fidx[q];
    const int b  = q >> 10;
    const int hw = q & 1023;
    const float* zb = z + (size_t)b * BSTR + hw;
    float*       ob = out0 + (size_t)b * BSTR + hw;
    const float* e  = E + (size_t)idx * DIMK;
    float ls = 0.0f;
    for (int c0 = 0; c0 < DIMK; ++c0) {
        float ev = e[c0];
        float zv = zb[(size_t)c0 * CSTR];
        float d  = ev - zv;
        ls = fmaf(d, d, ls);
        ob[(size_t)c0 * CSTR] = ev;
    }
    red[t] = ls;
    __syncthreads();
    for (int s = 128; s > 0; s >>= 1) {
        if (t < s) red[t] += red[t + s];
        __syncthreads();
    }
    if (t == 0) atomicAdd(acc, red[0]);
}

__global__ void k_loss(const float* __restrict__ acc, float* __restrict__ out_loss) {
    *out_loss = 1.25f * (*acc) * (1.0f / 2097152.0f);
}

extern "C" void kernel_launch(void* const* d_in, const int* in_sizes, int n_in,
                              void* d_out, int out_size, void* d_ws, size_t ws_size,
                              hipStream_t stream) {
    const float* z = (const float*)d_in[0];   // [8,256,32,32] fp32
    const float* E = (const float*)d_in[1];   // [16384,256] fp32

    float* out0     = (float*)d_out;
    float* out_loss = (float*)d_out + 2097152;
    float* out_idx  = (float*)d_out + 2097153;

    float*    acc  = (float*)d_ws;
    float*    ee   = (float*)((char*)d_ws + WS_EE_OFF);
    float*    zz   = (float*)((char*)d_ws + WS_ZZ_OFF);
    u32*      gmin = (u32*)  ((char*)d_ws + WS_GMIN_OFF);
    u32*      cnt  = (u32*)  ((char*)d_ws + WS_CNT_OFF);
    int*      fidx = (int*)  ((char*)d_ws + WS_FIDX_OFF);
    ushort_t* zb16 = (ushort_t*)((char*)d_ws + WS_ZB_OFF);
    u64*      cand = (u64*)  ((char*)d_ws + WS_CAND_OFF);

    k_prep<<<NE / 256, 256, 0, stream>>>(z, E, ee, zz, gmin, cnt, acc);
    k_zt<<<512, 256, 0, stream>>>(z, zb16);
    k_mfma_filter<<<(NQ / BR) * (NE / BC), 256, 0, stream>>>(zb16, E, ee, gmin, cnt, cand);
    k_rescore<<<NQ, 64, 0, stream>>>(z, E, zz, ee, cnt, cand, fidx, out_idx);
    k_finalize<<<NQ / 256, 256, 0, stream>>>(z, E, fidx, out0, acc);
    k_loss<<<1, 1, 0, stream>>>(acc, out_loss);
}

// Round 6
// 412.071 us; speedup vs baseline: 4.7978x; 1.2442x over previous
//
#include <hip/hip_runtime.h>
#include <stdint.h>

typedef unsigned int u32;
typedef unsigned long long u64;
typedef unsigned short ushort_t;
typedef short bf16x8 __attribute__((ext_vector_type(8)));
typedef float f32x4  __attribute__((ext_vector_type(4)));

// Problem constants
#define NQ    8192
#define DIMK  256
#define NE    16384
#define CSTR  1024
#define BSTR  262144

#define SLOTS 128
#define CMARG 2.5e-4f   // np tie window (~9e-5) + 2x worst-case bf16 rnd error (~5e-5 each)

// ws layout (bytes): total ~8.6 MB (proven ws >= 10.2 MB in round 4)
#define WS_EE    256        // float ee[16384]
#define WS_ZZ    65792      // float zz[8192]
#define WS_GMIN  98560      // u32 gmin[8192]
#define WS_CNT   131328     // u32 cnt[8192]
#define WS_FIDX  164096     // int fidx[8192]
#define WS_CAND  196864     // u64 cand[8192*128] = 8 MB

__device__ __forceinline__ u32 fmap(float f) {
    union { float f; u32 u; } x; x.f = f;
    return (x.u & 0x80000000u) ? ~x.u : (x.u | 0x80000000u);
}
__device__ __forceinline__ float funmap(u32 u) {
    union { float f; u32 u; } x;
    x.u = (u & 0x80000000u) ? (u ^ 0x80000000u) : ~u;
    return x.f;
}
// pack two fp32 -> two bf16 (round-half-up: err <= 2^-9 rel, same worst case as RNE)
__device__ __forceinline__ u32 pkbf(float lo, float hi) {
    u32 a = __float_as_uint(lo) + 0x8000u;
    u32 b = __float_as_uint(hi) + 0x8000u;
    return __builtin_amdgcn_perm(b, a, 0x07060302u);  // [b.hi16, a.hi16]
}

// ---- numpy einsum dot replica: SSE baseline (W=4, no FMA) — validated round 3/4 ----
__device__ __forceinline__ float np_einsum_dot(const float* __restrict__ zr, int zstride,
                                               const float* __restrict__ er) {
    float a0 = 0.0f, a1 = 0.0f, a2 = 0.0f, a3 = 0.0f;
    for (int s = 0; s < 64; ++s) {
        const int k = s * 4;
        a0 = __fadd_rn(a0, __fmul_rn(zr[(size_t)(k + 0) * zstride], er[k + 0]));
        a1 = __fadd_rn(a1, __fmul_rn(zr[(size_t)(k + 1) * zstride], er[k + 1]));
        a2 = __fadd_rn(a2, __fmul_rn(zr[(size_t)(k + 2) * zstride], er[k + 2]));
        a3 = __fadd_rn(a3, __fmul_rn(zr[(size_t)(k + 3) * zstride], er[k + 3]));
    }
    return __fadd_rn(__fadd_rn(a0, a1), __fadd_rn(a2, a3));
}

// numpy pairwise sum-of-squares, wave-parallel (16 lanes/row), bitwise np order
// (shfl-xor tree == np's ((r0+r1)+(r2+r3))+((r4+r5)+(r6+r7)) by fadd commutativity)
__global__ __launch_bounds__(256)
void k_prep(const float* __restrict__ z, const float* __restrict__ E,
            float* __restrict__ ee, float* __restrict__ zz,
            u32* __restrict__ gmin, u32* __restrict__ cnt, float* __restrict__ acc) {
    const int t = threadIdx.x;
    if (blockIdx.x == 0 && t == 0) *acc = 0.0f;
    const int g = t >> 4, s = t & 15;
    const int row = blockIdx.x * 16 + g;
    const float* p;
    int stride;
    if (row < NE) { p = E + (size_t)row * DIMK; stride = 1; }
    else {
        const int q = row - NE;
        const int b = q >> 10, hw = q & 1023;
        p = z + (size_t)b * BSTR + hw; stride = CSTR;
        if (s == 0) { gmin[q] = 0xFFFFFFFFu; cnt[q] = 0u; }
    }
    const int h = s >> 3, j = s & 7;
    const float* pp = p + (size_t)(h * 128 + j) * stride;
    float v = pp[0];
    float r = __fmul_rn(v, v);
    for (int i = 1; i < 16; ++i) {
        v = pp[(size_t)(i * 8) * stride];
        r = __fadd_rn(r, __fmul_rn(v, v));
    }
    r = __fadd_rn(r, __shfl_xor(r, 1, 16));
    r = __fadd_rn(r, __shfl_xor(r, 2, 16));
    r = __fadd_rn(r, __shfl_xor(r, 4, 16));
    r = __fadd_rn(r, __shfl_xor(r, 8, 16));   // full np pairwise sum, all 16 lanes
    if (s == 0) {
        if (row < NE) ee[row] = r;
        else          zz[row - NE] = r;
    }
}

// bf16 MFMA filter: 64 row-blocks x 8 col-chunks; A (128x256) in registers,
// sweep 16 col-tiles of 128; streaming collect with history threshold.
__global__ __launch_bounds__(256, 2)
void k_filter(const float* __restrict__ z, const float* __restrict__ E,
              const float* __restrict__ ee,
              u32* __restrict__ gmin, u32* __restrict__ cnt, u64* __restrict__ cand) {
    __shared__ ushort_t Bl[32768];          // 64 KB, XOR-swizzled [row][k]
    __shared__ u32 rowthr[128];
    char* lds = (char*)Bl;

    const int t    = threadIdx.x;
    const int bid  = blockIdx.x;            // row-block fastest (gmin staggering)
    const int n0   = (bid & 63) * 128;
    const int j0c  = (bid >> 6) * 2048;
    const int b    = n0 >> 10, hw0 = n0 & 1023;
    const int w    = t >> 6, lane = t & 63, quad = lane >> 4, l15 = lane & 15;
    const int wr   = (w >> 1) * 64, wc = (w & 1) * 64;

    if (t < 128) rowthr[t] = 0xFFFFFFFFu;

    // ---- stage A once: z[b][k][hw] -> bf16 LDS [row][k], swizzled ----
    {
        const int rbase = (t & 31) * 4;
        const int ksub  = (t >> 5) * 2;
        for (int p = 0; p < 16; ++p) {
            const int k0 = p * 16 + ksub;
            float4 f0 = *(const float4*)(z + (size_t)b * BSTR + (size_t)k0 * CSTR + hw0 + rbase);
            float4 f1 = *(const float4*)(z + (size_t)b * BSTR + (size_t)(k0 + 1) * CSTR + hw0 + rbase);
            const float a0[4] = {f0.x, f0.y, f0.z, f0.w};
            const float a1[4] = {f1.x, f1.y, f1.z, f1.w};
#pragma unroll
            for (int i = 0; i < 4; ++i) {
                const int row = rbase + i;
                *(u32*)(lds + row * 512 + ((k0 * 2) ^ ((row & 7) << 4))) = pkbf(a0[i], a1[i]);
            }
        }
    }
    __syncthreads();
    // A fragments -> registers (128 VGPRs)
    bf16x8 af[4][8];
#pragma unroll
    for (int fi = 0; fi < 4; ++fi) {
        const int row = wr + fi * 16 + l15;
#pragma unroll
        for (int kc = 0; kc < 8; ++kc)
            af[fi][kc] = *(const bf16x8*)(lds + row * 512 + ((kc * 64 + quad * 16) ^ ((row & 7) << 4)));
    }
    __syncthreads();

    // sweep: it 0..16; it==16 re-does tile 0 with tight thresholds (bootstrap)
    for (int it = 0; it <= 16; ++it) {
        const int ct = (it == 16) ? 0 : it;
        const bool collect = (it > 0);
        const int j0 = j0c + ct * 128;

        // ---- stage B tile (128 cols x 256 k) fp32 -> bf16, swizzled ----
        {
            const int csub = lane >> 5;         // 0/1
            const int osub = lane & 31;         // 32B chunk within row
            for (int ii = 0; ii < 16; ++ii) {
                const int col = w * 32 + ii * 2 + csub;
                const float* src = E + (size_t)(j0 + col) * DIMK + osub * 8;
                float4 f0 = *(const float4*)(src);
                float4 f1 = *(const float4*)(src + 4);
                uint4 pk;
                pk.x = pkbf(f0.x, f0.y); pk.y = pkbf(f0.z, f0.w);
                pk.z = pkbf(f1.x, f1.y); pk.w = pkbf(f1.z, f1.w);
                *(uint4*)(lds + col * 512 + ((osub * 16) ^ ((col & 7) << 4))) = pk;
            }
        }
        __syncthreads();

        // ---- MFMA: 8 k-chunks x 4x4 fragments ----
        f32x4 acc[4][4];
#pragma unroll
        for (int fi = 0; fi < 4; ++fi)
#pragma unroll
            for (int fj = 0; fj < 4; ++fj)
#pragma unroll
                for (int r = 0; r < 4; ++r) acc[fi][fj][r] = 0.0f;
#pragma unroll
        for (int kc = 0; kc < 8; ++kc) {
            bf16x8 bfr[4];
#pragma unroll
            for (int fj = 0; fj < 4; ++fj) {
                const int col = wc + fj * 16 + l15;
                bfr[fj] = *(const bf16x8*)(lds + col * 512 + ((kc * 64 + quad * 16) ^ ((col & 7) << 4)));
            }
#pragma unroll
            for (int fi = 0; fi < 4; ++fi)
#pragma unroll
                for (int fj = 0; fj < 4; ++fj)
                    acc[fi][fj] = __builtin_amdgcn_mfma_f32_16x16x32_bf16(
                        af[fi][kc], bfr[fj], acc[fi][fj], 0, 0, 0);
        }
        __syncthreads();   // frag reads done before next tile's staging

        // ---- epilogue: v = ee - 2*dot; history-threshold collect ----
        float eev[4];
#pragma unroll
        for (int fj = 0; fj < 4; ++fj) eev[fj] = ee[j0 + wc + fj * 16 + l15];

#pragma unroll
        for (int fi = 0; fi < 4; ++fi) {
#pragma unroll
            for (int r = 0; r < 4; ++r) {
                float vv[4];
#pragma unroll
                for (int fj = 0; fj < 4; ++fj) vv[fj] = eev[fj] - 2.0f * acc[fi][fj][r];
                float m = fminf(fminf(vv[0], vv[1]), fminf(vv[2], vv[3]));
                m = fminf(m, __shfl_xor(m, 1, 16));
                m = fminf(m, __shfl_xor(m, 2, 16));
                m = fminf(m, __shfl_xor(m, 4, 16));
                m = fminf(m, __shfl_xor(m, 8, 16));
                const int rl = wr + fi * 16 + quad * 4 + r;
                const u32 pre = rowthr[rl];                 // history BEFORE own update
                if (l15 == 0) atomicMin(&rowthr[rl], fmap(m));
                if (collect) {
                    // pre >= final row min always => thr complete for winner
                    const float thr = funmap(pre) + CMARG;
#pragma unroll
                    for (int fj = 0; fj < 4; ++fj) {
                        if (vv[fj] <= thr) {
                            const int rg = n0 + rl;
                            u32 p = atomicAdd(&cnt[rg], 1u);
                            if (p < SLOTS)
                                cand[(size_t)rg * SLOTS + p] =
                                    ((u64)fmap(vv[fj]) << 32) | (u32)(j0 + wc + fj * 16 + l15);
                        }
                    }
                }
            }
        }
        // periodic cross-block threshold exchange (monotone-safe, no barrier)
        if ((it & 3) == 3 && t < 128) {
            const u32 lv = rowthr[t];
            const u32 old = atomicMin(&gmin[n0 + t], lv);
            if (old < lv) atomicMin(&rowthr[t], old);
        }
    }
}

// numpy-bitwise rescore over collected candidates (winner provably in set)
__global__ __launch_bounds__(64)
void k_rescore(const float* __restrict__ z, const float* __restrict__ E,
               const float* __restrict__ zz, const float* __restrict__ ee,
               const u32* __restrict__ cnt, const u64* __restrict__ cand,
               int* __restrict__ fidx, float* __restrict__ out_idx) {
    const int q = blockIdx.x;
    const int t = threadIdx.x;
    const int b = q >> 10, hw = q & 1023;
    const u32 n = min(cnt[q], (u32)SLOTS);

    u64 c1 = (u32)t < n        ? cand[(size_t)q * SLOTS + t]      : 0xFFFFFFFFFFFFFFFFULL;
    u64 c2 = (u32)(t + 64) < n ? cand[(size_t)q * SLOTS + t + 64] : 0xFFFFFFFFFFFFFFFFULL;

    u32 mv = (u32)(c1 >> 32);
    { u32 m2 = (u32)(c2 >> 32); if (m2 < mv) mv = m2; }
#pragma unroll
    for (int off = 1; off < 64; off <<= 1) {
        u32 o = __shfl_xor(mv, off, 64);
        if (o < mv) mv = o;
    }
    const float thr = funmap(mv) + CMARG;

    u64 best = 0xFFFFFFFFFFFFFFFFULL;
#pragma unroll
    for (int s = 0; s < 2; ++s) {
        const u64 c = s ? c2 : c1;
        if (c != 0xFFFFFFFFFFFFFFFFULL && funmap((u32)(c >> 32)) <= thr) {
            const int j = (int)(c & 0xFFFFFFFFULL) & (NE - 1);   // mask: OOB-proof
            const float ze = np_einsum_dot(z + (size_t)b * BSTR + hw, CSTR, E + (size_t)j * DIMK);
            const float t1 = __fadd_rn(zz[q], ee[j]);
            const float d  = __fsub_rn(t1, __fmul_rn(2.0f, ze));
            u64 key = ((u64)fmap(d) << 32) | (u32)j;   // ties -> lowest j
            if (key < best) best = key;
        }
    }
#pragma unroll
    for (int off = 1; off < 64; off <<= 1) {
        u64 o = __shfl_xor(best, off, 64);
        if (o < best) best = o;
    }
    if (t == 0) {
        const int bj = (int)(best & 0xFFFFFFFFULL) & (NE - 1);
        fidx[q] = bj;
        out_idx[q] = (float)bj;
    }
}

// gather + transpose + loss, LDS-transposed for coalesced writes
__global__ __launch_bounds__(256)
void k_finalize(const float* __restrict__ z, const float* __restrict__ E,
                const int* __restrict__ fidx,
                float* __restrict__ out0, float* __restrict__ acc) {
    __shared__ float T[256 * 33];
    __shared__ float red[256];
    const int t  = threadIdx.x;
    const int q0 = blockIdx.x * 256;
    const int b  = q0 >> 10, hw0 = q0 & 1023;
    const int myidx = fidx[q0 + t] & (NE - 1);   // mask: OOB-proof
    const int hwl = t & 63, cg = t >> 6;
    float ls = 0.0f;
    for (int ch = 0; ch < 8; ++ch) {
        const int c0 = ch * 32;
        const float* er = E + (size_t)myidx * DIMK + c0;
#pragma unroll
        for (int i = 0; i < 8; ++i) {
            float4 f = *(const float4*)(er + i * 4);
            T[t * 33 + i * 4 + 0] = f.x;
            T[t * 33 + i * 4 + 1] = f.y;
            T[t * 33 + i * 4 + 2] = f.z;
            T[t * 33 + i * 4 + 3] = f.w;
        }
        __syncthreads();
#pragma unroll
        for (int qq = 0; qq < 4; ++qq) {
#pragma unroll
            for (int i = 0; i < 8; ++i) {
                const int cl = cg * 8 + i;
                const int ql = qq * 64 + hwl;
                const float e = T[ql * 33 + cl];
                const size_t o = (size_t)b * BSTR + (size_t)(c0 + cl) * CSTR + hw0 + ql;
                const float d = e - z[o];
                ls = fmaf(d, d, ls);
                out0[o] = e;
            }
        }
        __syncthreads();
    }
    red[t] = ls;
    __syncthreads();
    for (int s = 128; s > 0; s >>= 1) {
        if (t < s) red[t] += red[t + s];
        __syncthreads();
    }
    if (t == 0) atomicAdd(acc, red[0]);
}

__global__ void k_loss(const float* __restrict__ acc, float* __restrict__ out_loss) {
    *out_loss = 1.25f * (*acc) * (1.0f / 2097152.0f);
}

extern "C" void kernel_launch(void* const* d_in, const int* in_sizes, int n_in,
                              void* d_out, int out_size, void* d_ws, size_t ws_size,
                              hipStream_t stream) {
    const float* z = (const float*)d_in[0];   // [8,256,32,32] fp32
    const float* E = (const float*)d_in[1];   // [16384,256] fp32

    float* out0     = (float*)d_out;
    float* out_loss = (float*)d_out + 2097152;
    float* out_idx  = (float*)d_out + 2097153;

    float* acc  = (float*)d_ws;
    float* ee   = (float*)((char*)d_ws + WS_EE);
    float* zz   = (float*)((char*)d_ws + WS_ZZ);
    u32*   gmin = (u32*)  ((char*)d_ws + WS_GMIN);
    u32*   cnt  = (u32*)  ((char*)d_ws + WS_CNT);
    int*   fidx = (int*)  ((char*)d_ws + WS_FIDX);
    u64*   cand = (u64*)  ((char*)d_ws + WS_CAND);

    k_prep<<<(NE + NQ) / 16, 256, 0, stream>>>(z, E, ee, zz, gmin, cnt, acc);  // 1536 blocks (16 rows/block)
    k_filter<<<512, 256, 0, stream>>>(z, E, ee, gmin, cnt, cand);
    k_rescore<<<NQ, 64, 0, stream>>>(z, E, zz, ee, cnt, cand, fidx, out_idx);
    k_finalize<<<NQ / 256, 256, 0, stream>>>(z, E, fidx, out0, acc);
    k_loss<<<1, 1, 0, stream>>>(acc, out_loss);
}

// Round 7
// 341.812 us; speedup vs baseline: 5.7840x; 1.2056x over previous
//
#include <hip/hip_runtime.h>
#include <stdint.h>

typedef unsigned int u32;
typedef unsigned long long u64;
typedef unsigned short u16;
typedef unsigned short ushort_t;
typedef short bf16x8 __attribute__((ext_vector_type(8)));
typedef float f32x4  __attribute__((ext_vector_type(4)));

// Problem constants
#define NQ    8192
#define DIMK  256
#define NE    16384
#define CSTR  1024
#define BSTR  262144

#define SLOTS 128
#define CMARG 2.5e-4f   // np tie window (~9e-5) + 2x worst-case bf16 rnd error

// ws layout (bytes): total 10,649,856 <= 10,682,624 proven in round 4
#define WS_EE    256        // float ee[16384]
#define WS_ZZ    65792      // float zz[8192]
#define WS_GMIN  98560      // u32 gmin[8192]
#define WS_CNT   131328     // u32 cnt[8192]
#define WS_CAND  164096     // u16 cand[8192*128] = 2 MB
#define WS_EP    2261248    // ushort Ep[16384*256] = 8 MB (permuted bf16 E)

__device__ __forceinline__ u32 fmap(float f) {
    union { float f; u32 u; } x; x.f = f;
    return (x.u & 0x80000000u) ? ~x.u : (x.u | 0x80000000u);
}
__device__ __forceinline__ float funmap(u32 u) {
    union { float f; u32 u; } x;
    x.u = (u & 0x80000000u) ? (u ^ 0x80000000u) : ~u;
    return x.f;
}
// pack two fp32 -> two bf16 (round-half-up; error budget covered by CMARG, proven R4-R6)
__device__ __forceinline__ u32 pkbf(float lo, float hi) {
    u32 a = __float_as_uint(lo) + 0x8000u;
    u32 b = __float_as_uint(hi) + 0x8000u;
    return __builtin_amdgcn_perm(b, a, 0x07060302u);
}

// ---- numpy einsum dot replica: SSE baseline (W=4, no FMA) — validated R3-R6 ----
__device__ __forceinline__ float np_einsum_dot(const float* __restrict__ zr, int zstride,
                                               const float* __restrict__ er) {
    float a0 = 0.0f, a1 = 0.0f, a2 = 0.0f, a3 = 0.0f;
    for (int s = 0; s < 64; ++s) {
        const int k = s * 4;
        a0 = __fadd_rn(a0, __fmul_rn(zr[(size_t)(k + 0) * zstride], er[k + 0]));
        a1 = __fadd_rn(a1, __fmul_rn(zr[(size_t)(k + 1) * zstride], er[k + 1]));
        a2 = __fadd_rn(a2, __fmul_rn(zr[(size_t)(k + 2) * zstride], er[k + 2]));
        a3 = __fadd_rn(a3, __fmul_rn(zr[(size_t)(k + 3) * zstride], er[k + 3]));
    }
    return __fadd_rn(__fadd_rn(a0, a1), __fadd_rn(a2, a3));
}

// blocks 0..1023: E rows (ee + Ep permuted-bf16 conversion); 1024..1535: z rows (zz + init)
__global__ __launch_bounds__(256)
void k_prep(const float* __restrict__ z, const float* __restrict__ E,
            float* __restrict__ ee, float* __restrict__ zz,
            u32* __restrict__ gmin, u32* __restrict__ cnt, float* __restrict__ acc,
            ushort_t* __restrict__ Ep) {
    const int t = threadIdx.x;
    const int bid = blockIdx.x;
    if (bid == 0 && t == 0) *acc = 0.0f;
    const int g = t >> 4, s = t & 15;
    const int row = bid * 16 + g;
    const float* p;
    int stride;
    if (row < NE) { p = E + (size_t)row * DIMK; stride = 1; }
    else {
        const int q = row - NE;
        const int b = q >> 10, hw = q & 1023;
        p = z + (size_t)b * BSTR + hw; stride = CSTR;
        if (s == 0) { gmin[q] = 0xFFFFFFFFu; cnt[q] = 0u; }
    }
    // np pairwise sum of squares, 16 lanes/row (bitwise np order via fadd commutativity)
    const int h = s >> 3, j = s & 7;
    const float* pp = p + (size_t)(h * 128 + j) * stride;
    float v = pp[0];
    float r = __fmul_rn(v, v);
    for (int i = 1; i < 16; ++i) {
        v = pp[(size_t)(i * 8) * stride];
        r = __fadd_rn(r, __fmul_rn(v, v));
    }
    r = __fadd_rn(r, __shfl_xor(r, 1, 16));
    r = __fadd_rn(r, __shfl_xor(r, 2, 16));
    r = __fadd_rn(r, __shfl_xor(r, 4, 16));
    r = __fadd_rn(r, __shfl_xor(r, 8, 16));
    if (s == 0) {
        if (row < NE) ee[row] = r;
        else          zz[row - NE] = r;
    }
    if (bid < 1024) {
        // Ep conversion for col-group g=bid: chunk c = kc*64 + quad*16 + l15 holds
        // bf16 E[bid*16 + l15][kc*32 + quad*8 .. +7]; rows are L1-hot from above.
#pragma unroll
        for (int i = 0; i < 2; ++i) {
            const int c    = t + i * 256;
            const int kc   = c >> 6;
            const int lane = c & 63;
            const int quad = lane >> 4, l15 = lane & 15;
            const float* src = E + (size_t)(bid * 16 + l15) * DIMK + kc * 32 + quad * 8;
            float4 f0 = *(const float4*)(src);
            float4 f1 = *(const float4*)(src + 4);
            uint4 pk;
            pk.x = pkbf(f0.x, f0.y); pk.y = pkbf(f0.z, f0.w);
            pk.z = pkbf(f1.x, f1.y); pk.w = pkbf(f1.z, f1.w);
            *(uint4*)((char*)Ep + (size_t)bid * 8192 + (size_t)c * 16) = pk;
        }
    }
}

// MFMA filter: A (128x256 bf16) in registers; B frags direct from permuted Ep
// (stride-1 coalesced global loads, NO LDS / NO barriers in the sweep).
// chunk = bid&7 -> XCD-pinned 1MB Ep slice (L2-resident).
__global__ __launch_bounds__(256, 2)
void k_filter(const float* __restrict__ z, const ushort_t* __restrict__ Ep,
              const float* __restrict__ ee,
              u32* __restrict__ gmin, u32* __restrict__ cnt, u16* __restrict__ cand) {
    __shared__ ushort_t Az[32768];          // 64 KB A staging (one-time)
    __shared__ u32 rowthr[128];
    char* lds = (char*)Az;

    const int t    = threadIdx.x;
    const int bid  = blockIdx.x;
    const int chunk = bid & 7;              // 8 col-chunks <-> 8 XCDs
    const int rb    = bid >> 3;             // 64 row-blocks
    const int n0   = rb * 128;
    const int j0c  = chunk * 2048;
    const int b    = n0 >> 10, hw0 = n0 & 1023;
    const int w    = t >> 6, lane = t & 63, quad = lane >> 4, l15 = lane & 15;
    const int wr   = (w >> 1) * 64, wc = (w & 1) * 64;

    if (t < 128) rowthr[t] = 0xFFFFFFFFu;

    // ---- stage A once: z[b][k][hw] -> bf16 LDS [row][k] swizzled (R6-proven) ----
    {
        const int rbase = (t & 31) * 4;
        const int ksub  = (t >> 5) * 2;
        for (int p = 0; p < 16; ++p) {
            const int k0 = p * 16 + ksub;
            float4 f0 = *(const float4*)(z + (size_t)b * BSTR + (size_t)k0 * CSTR + hw0 + rbase);
            float4 f1 = *(const float4*)(z + (size_t)b * BSTR + (size_t)(k0 + 1) * CSTR + hw0 + rbase);
            const float a0[4] = {f0.x, f0.y, f0.z, f0.w};
            const float a1[4] = {f1.x, f1.y, f1.z, f1.w};
#pragma unroll
            for (int i = 0; i < 4; ++i) {
                const int row = rbase + i;
                *(u32*)(lds + row * 512 + ((k0 * 2) ^ ((row & 7) << 4))) = pkbf(a0[i], a1[i]);
            }
        }
    }
    __syncthreads();
    bf16x8 af[4][8];
#pragma unroll
    for (int fi = 0; fi < 4; ++fi) {
        const int row = wr + fi * 16 + l15;
#pragma unroll
        for (int kc = 0; kc < 8; ++kc)
            af[fi][kc] = *(const bf16x8*)(lds + row * 512 + ((kc * 64 + quad * 16) ^ ((row & 7) << 4)));
    }
    __syncthreads();   // last barrier — sweep below is barrier-free

    // sweep tiles; it==16 re-visits tile 0 with tight thresholds (bootstrap)
    for (int it = 0; it <= 16; ++it) {
        const int ct = (it == 16) ? 0 : it;
        const bool collect = (it > 0);
        const int j0 = j0c + ct * 128;
        const int Gbase = (j0 + wc) >> 4;   // global 16-col group of fj=0
        const ushort_t* pb = Ep + ((size_t)Gbase * 8 * 64 + (size_t)quad * 16 + l15) * 8;

        float eev[4];
#pragma unroll
        for (int fj = 0; fj < 4; ++fj) eev[fj] = ee[j0 + wc + fj * 16 + l15];

        f32x4 acc[4][4];
#pragma unroll
        for (int fi = 0; fi < 4; ++fi)
#pragma unroll
            for (int fj = 0; fj < 4; ++fj)
#pragma unroll
                for (int r = 0; r < 4; ++r) acc[fi][fj][r] = 0.0f;

#pragma unroll
        for (int kc = 0; kc < 8; ++kc) {
            bf16x8 bfr[4];
#pragma unroll
            for (int fj = 0; fj < 4; ++fj)
                bfr[fj] = *(const bf16x8*)(pb + ((size_t)fj * 8 * 64 + (size_t)kc * 64) * 8);
#pragma unroll
            for (int fi = 0; fi < 4; ++fi)
#pragma unroll
                for (int fj = 0; fj < 4; ++fj)
                    acc[fi][fj] = __builtin_amdgcn_mfma_f32_16x16x32_bf16(
                        af[fi][kc], bfr[fj], acc[fi][fj], 0, 0, 0);
        }

        // epilogue: v = ee - 2*dot; history-threshold streaming collect (R6-proven)
#pragma unroll
        for (int fi = 0; fi < 4; ++fi) {
#pragma unroll
            for (int r = 0; r < 4; ++r) {
                float vv[4];
#pragma unroll
                for (int fj = 0; fj < 4; ++fj) vv[fj] = eev[fj] - 2.0f * acc[fi][fj][r];
                float m = fminf(fminf(vv[0], vv[1]), fminf(vv[2], vv[3]));
                m = fminf(m, __shfl_xor(m, 1, 16));
                m = fminf(m, __shfl_xor(m, 2, 16));
                m = fminf(m, __shfl_xor(m, 4, 16));
                m = fminf(m, __shfl_xor(m, 8, 16));
                const int rl = wr + fi * 16 + quad * 4 + r;
                const u32 pre = rowthr[rl];                 // history BEFORE own update
                if (l15 == 0) atomicMin(&rowthr[rl], fmap(m));
                if (collect) {
                    // pre >= global row min >= v(winner) - CMARG => winner always kept
                    const float thr = funmap(pre) + CMARG;
#pragma unroll
                    for (int fj = 0; fj < 4; ++fj) {
                        if (vv[fj] <= thr) {
                            const int rg = n0 + rl;
                            u32 p = atomicAdd(&cnt[rg], 1u);
                            if (p < SLOTS)
                                cand[(size_t)rg * SLOTS + p] = (u16)(j0 + wc + fj * 16 + l15);
                        }
                    }
                }
            }
        }
        // every-tile cross-chunk threshold exchange (monotone-safe, no barrier)
        if (t < 128) {
            const u32 lv = rowthr[t];
            const u32 old = atomicMin(&gmin[n0 + t], lv);
            if (old < lv) atomicMin(&rowthr[t], old);
        }
    }
}

// numpy-bitwise rescore of ALL collected candidates (winner provably in set)
__global__ __launch_bounds__(64)
void k_rescore(const float* __restrict__ z, const float* __restrict__ E,
               const float* __restrict__ zz, const float* __restrict__ ee,
               const u32* __restrict__ cnt, const u16* __restrict__ cand,
               float* __restrict__ out_idx) {
    const int q = blockIdx.x;
    const int t = threadIdx.x;
    const int b = q >> 10, hw = q & 1023;
    const u32 n = min(cnt[q], (u32)SLOTS);

    u64 best = 0xFFFFFFFFFFFFFFFFULL;
#pragma unroll
    for (int s = 0; s < 2; ++s) {
        const u32 slot = (u32)t + s * 64;
        if (slot < n) {
            const int j = (int)cand[(size_t)q * SLOTS + slot];
            const float ze = np_einsum_dot(z + (size_t)b * BSTR + hw, CSTR, E + (size_t)j * DIMK);
            const float t1 = __fadd_rn(zz[q], ee[j]);
            const float d  = __fsub_rn(t1, __fmul_rn(2.0f, ze));
            u64 key = ((u64)fmap(d) << 32) | (u32)j;   // ties -> lowest j
            if (key < best) best = key;
        }
    }
#pragma unroll
    for (int off = 1; off < 64; off <<= 1) {
        u64 o = __shfl_xor(best, off, 64);
        if (o < best) best = o;
    }
    if (t == 0) out_idx[q] = (float)(int)(best & 0xFFFFFFFFULL);
}

// gather + transpose + loss; 256 blocks (32 q-groups x 8 c-groups)
__global__ __launch_bounds__(256)
void k_finalize(const float* __restrict__ z, const float* __restrict__ E,
                const float* __restrict__ out_idx,
                float* __restrict__ out0, float* __restrict__ acc) {
    __shared__ float T[256 * 33];
    __shared__ float red[256];
    const int t  = threadIdx.x;
    const int qg = blockIdx.x >> 3;
    const int ch = blockIdx.x & 7;
    const int q0 = qg * 256;
    const int c0 = ch * 32;
    const int b  = q0 >> 10, hw0 = q0 & 1023;
    const int idx = ((int)out_idx[q0 + t]) & (NE - 1);
    const float* er = E + (size_t)idx * DIMK + c0;
#pragma unroll
    for (int i = 0; i < 8; ++i) {
        float4 f = *(const float4*)(er + i * 4);
        T[t * 33 + i * 4 + 0] = f.x;
        T[t * 33 + i * 4 + 1] = f.y;
        T[t * 33 + i * 4 + 2] = f.z;
        T[t * 33 + i * 4 + 3] = f.w;
    }
    __syncthreads();
    float ls = 0.0f;
#pragma unroll 4
    for (int cc = 0; cc < 32; ++cc) {
        const float e = T[t * 33 + cc];           // value for q = q0+t? NO: see below
        (void)e;
        // transposed read: value for output (c0+cc, hw0+t) is T[t_q=t][cc] written by thread t
        const float ev = T[t * 33 + cc];
        const size_t o = (size_t)b * BSTR + (size_t)(c0 + cc) * CSTR + hw0 + t;
        const float d = ev - z[o];
        ls = fmaf(d, d, ls);
        out0[o] = ev;
    }
    red[t] = ls;
    __syncthreads();
    for (int s = 128; s > 0; s >>= 1) {
        if (t < s) red[t] += red[t + s];
        __syncthreads();
    }
    if (t == 0) atomicAdd(acc, red[0]);
}

__global__ void k_loss(const float* __restrict__ acc, float* __restrict__ out_loss) {
    *out_loss = 1.25f * (*acc) * (1.0f / 2097152.0f);
}

extern "C" void kernel_launch(void* const* d_in, const int* in_sizes, int n_in,
                              void* d_out, int out_size, void* d_ws, size_t ws_size,
                              hipStream_t stream) {
    const float* z = (const float*)d_in[0];   // [8,256,32,32] fp32
    const float* E = (const float*)d_in[1];   // [16384,256] fp32

    float* out0     = (float*)d_out;
    float* out_loss = (float*)d_out + 2097152;
    float* out_idx  = (float*)d_out + 2097153;

    float*    acc  = (float*)d_ws;
    float*    ee   = (float*)((char*)d_ws + WS_EE);
    float*    zz   = (float*)((char*)d_ws + WS_ZZ);
    u32*      gmin = (u32*)  ((char*)d_ws + WS_GMIN);
    u32*      cnt  = (u32*)  ((char*)d_ws + WS_CNT);
    u16*      cand = (u16*)  ((char*)d_ws + WS_CAND);
    ushort_t* Ep   = (ushort_t*)((char*)d_ws + WS_EP);

    k_prep<<<1536, 256, 0, stream>>>(z, E, ee, zz, gmin, cnt, acc, Ep);
    k_filter<<<512, 256, 0, stream>>>(z, Ep, ee, gmin, cnt, cand);
    k_rescore<<<NQ, 64, 0, stream>>>(z, E, zz, ee, cnt, cand, out_idx);
    k_finalize<<<256, 256, 0, stream>>>(z, E, out_idx, out0, acc);
    k_loss<<<1, 1, 0, stream>>>(acc, out_loss);
}

// Round 9
// 307.415 us; speedup vs baseline: 6.4312x; 1.1119x over previous
//
#include <hip/hip_runtime.h>
#include <stdint.h>

typedef unsigned int u32;
typedef unsigned long long u64;
typedef unsigned short u16;
typedef unsigned short ushort_t;
typedef short bf16x8 __attribute__((ext_vector_type(8)));
typedef float f32x4  __attribute__((ext_vector_type(4)));

// Problem constants
#define NQ    8192
#define DIMK  256
#define NE    16384
#define CSTR  1024
#define BSTR  262144

#define SLOTS 128
#define CMARG 2.5e-4f   // np tie window (~9e-5) + 2x worst-case bf16 rnd error

// ws layout (bytes): total 10,649,856 <= 10,682,624 proven in round 4
#define WS_EE    256        // float ee[16384]
#define WS_ZZ    65792      // float zz[8192]
#define WS_GMIN  98560      // u32 gmin[8192]
#define WS_CNT   131328     // u32 cnt[8192]
#define WS_CAND  164096     // u16 cand[8192*128] = 2 MB
#define WS_EP    2261248    // ushort Ep[16384*256] = 8 MB (permuted bf16 E)

// fmap(FLT_MAX): finite sentinel for rowthr — funmap() of it is FLT_MAX, NOT NaN.
// (R8 bug: 0xFFFFFFFF sentinel -> funmap = NaN -> any-skip gate never fired -> no collects)
#define THR_INIT 0xFF7FFFFFu

__device__ __forceinline__ u32 fmap(float f) {
    union { float f; u32 u; } x; x.f = f;
    return (x.u & 0x80000000u) ? ~x.u : (x.u | 0x80000000u);
}
__device__ __forceinline__ float funmap(u32 u) {
    union { float f; u32 u; } x;
    x.u = (u & 0x80000000u) ? (u ^ 0x80000000u) : ~u;
    return x.f;
}
// pack two fp32 -> two bf16 (round-half-up; error budget covered by CMARG, proven R4-R7)
__device__ __forceinline__ u32 pkbf(float lo, float hi) {
    u32 a = __float_as_uint(lo) + 0x8000u;
    u32 b = __float_as_uint(hi) + 0x8000u;
    return __builtin_amdgcn_perm(b, a, 0x07060302u);
}

// ---- numpy einsum dot replica: SSE baseline (W=4, no FMA) — validated R3-R7 ----
__device__ __forceinline__ float np_einsum_dot(const float* __restrict__ zr, int zstride,
                                               const float* __restrict__ er) {
    float a0 = 0.0f, a1 = 0.0f, a2 = 0.0f, a3 = 0.0f;
    for (int s = 0; s < 64; ++s) {
        const int k = s * 4;
        a0 = __fadd_rn(a0, __fmul_rn(zr[(size_t)(k + 0) * zstride], er[k + 0]));
        a1 = __fadd_rn(a1, __fmul_rn(zr[(size_t)(k + 1) * zstride], er[k + 1]));
        a2 = __fadd_rn(a2, __fmul_rn(zr[(size_t)(k + 2) * zstride], er[k + 2]));
        a3 = __fadd_rn(a3, __fmul_rn(zr[(size_t)(k + 3) * zstride], er[k + 3]));
    }
    return __fadd_rn(__fadd_rn(a0, a1), __fadd_rn(a2, a3));
}

// blocks 0..1023: E rows (ee + Ep permuted-bf16 conversion); 1024..1535: z rows (zz + init)
__global__ __launch_bounds__(256)
void k_prep(const float* __restrict__ z, const float* __restrict__ E,
            float* __restrict__ ee, float* __restrict__ zz,
            u32* __restrict__ gmin, u32* __restrict__ cnt, float* __restrict__ acc,
            ushort_t* __restrict__ Ep) {
    const int t = threadIdx.x;
    const int bid = blockIdx.x;
    if (bid == 0 && t == 0) *acc = 0.0f;
    const int g = t >> 4, s = t & 15;
    const int row = bid * 16 + g;
    const float* p;
    int stride;
    if (row < NE) { p = E + (size_t)row * DIMK; stride = 1; }
    else {
        const int q = row - NE;
        const int b = q >> 10, hw = q & 1023;
        p = z + (size_t)b * BSTR + hw; stride = CSTR;
        if (s == 0) { gmin[q] = 0xFFFFFFFFu; cnt[q] = 0u; }
    }
    // np pairwise sum of squares, 16 lanes/row (bitwise np order via fadd commutativity)
    const int h = s >> 3, j = s & 7;
    const float* pp = p + (size_t)(h * 128 + j) * stride;
    float v = pp[0];
    float r = __fmul_rn(v, v);
    for (int i = 1; i < 16; ++i) {
        v = pp[(size_t)(i * 8) * stride];
        r = __fadd_rn(r, __fmul_rn(v, v));
    }
    r = __fadd_rn(r, __shfl_xor(r, 1, 16));
    r = __fadd_rn(r, __shfl_xor(r, 2, 16));
    r = __fadd_rn(r, __shfl_xor(r, 4, 16));
    r = __fadd_rn(r, __shfl_xor(r, 8, 16));
    if (s == 0) {
        if (row < NE) ee[row] = r;
        else          zz[row - NE] = r;
    }
    if (bid < 1024) {
        // Ep: chunk c = kc*64 + quad*16 + l15 holds bf16 E[bid*16+l15][kc*32+quad*8 .. +7]
#pragma unroll
        for (int i = 0; i < 2; ++i) {
            const int c    = t + i * 256;
            const int kc   = c >> 6;
            const int lane = c & 63;
            const int quad = lane >> 4, l15 = lane & 15;
            const float* src = E + (size_t)(bid * 16 + l15) * DIMK + kc * 32 + quad * 8;
            float4 f0 = *(const float4*)(src);
            float4 f1 = *(const float4*)(src + 4);
            uint4 pk;
            pk.x = pkbf(f0.x, f0.y); pk.y = pkbf(f0.z, f0.w);
            pk.z = pkbf(f1.x, f1.y); pk.w = pkbf(f1.z, f1.w);
            *(uint4*)((char*)Ep + (size_t)bid * 8192 + (size_t)c * 16) = pk;
        }
    }
}

// MFMA filter: A (128x256 bf16) in registers; B frags from permuted Ep with
// explicit kc-distance-1 double-buffered prefetch (no barriers in sweep);
// any-skip epilogue. chunk = bid&7 -> XCD-pinned 1MB Ep slice.
__global__ __launch_bounds__(256, 2)
void k_filter(const float* __restrict__ z, const ushort_t* __restrict__ Ep,
              const float* __restrict__ ee,
              u32* __restrict__ gmin, u32* __restrict__ cnt, u16* __restrict__ cand) {
    __shared__ ushort_t Az[32768];          // 64 KB A staging (one-time)
    __shared__ u32 rowthr[128];
    char* lds = (char*)Az;

    const int t     = threadIdx.x;
    const int bid   = blockIdx.x;
    const int chunk = bid & 7;
    const int rb    = bid >> 3;
    const int n0    = rb * 128;
    const int j0c   = chunk * 2048;
    const int b     = n0 >> 10, hw0 = n0 & 1023;
    const int w     = t >> 6, lane = t & 63, quad = lane >> 4, l15 = lane & 15;
    const int wr    = (w >> 1) * 64, wc = (w & 1) * 64;

    if (t < 128) rowthr[t] = THR_INIT;      // finite sentinel (see THR_INIT note)

    // ---- stage A once: z[b][k][hw] -> bf16 LDS [row][k] swizzled (R6/R7-proven) ----
    {
        const int rbase = (t & 31) * 4;
        const int ksub  = (t >> 5) * 2;
        for (int p = 0; p < 16; ++p) {
            const int k0 = p * 16 + ksub;
            float4 f0 = *(const float4*)(z + (size_t)b * BSTR + (size_t)k0 * CSTR + hw0 + rbase);
            float4 f1 = *(const float4*)(z + (size_t)b * BSTR + (size_t)(k0 + 1) * CSTR + hw0 + rbase);
            const float a0[4] = {f0.x, f0.y, f0.z, f0.w};
            const float a1[4] = {f1.x, f1.y, f1.z, f1.w};
#pragma unroll
            for (int i = 0; i < 4; ++i) {
                const int row = rbase + i;
                *(u32*)(lds + row * 512 + ((k0 * 2) ^ ((row & 7) << 4))) = pkbf(a0[i], a1[i]);
            }
        }
    }
    __syncthreads();
    bf16x8 af[4][8];
#pragma unroll
    for (int fi = 0; fi < 4; ++fi) {
        const int row = wr + fi * 16 + l15;
#pragma unroll
        for (int kc = 0; kc < 8; ++kc)
            af[fi][kc] = *(const bf16x8*)(lds + row * 512 + ((kc * 64 + quad * 16) ^ ((row & 7) << 4)));
    }
    __syncthreads();   // last barrier — sweep below is barrier-free

    const int cbase = (j0c + wc) >> 4;   // 16-col group index of fj=0, tile 0 ref
    const size_t lofs = (size_t)lane * 8;

    bf16x8 bufA[4], bufB[4];
#define LOADB(dst, ct, kc)                                                        \
    {                                                                             \
        const int bg = cbase + (ct) * 8;                                          \
        const size_t ko = (size_t)((kc) * 64) * 8 + lofs;                         \
        _Pragma("unroll")                                                         \
        for (int fj = 0; fj < 4; ++fj)                                            \
            dst[fj] = *(const bf16x8*)(Ep + (size_t)(bg + fj) * 4096 + ko);       \
    }

    LOADB(bufA, 0, 0);   // prime the pipeline

    // sweep tiles; it==16 re-visits tile 0 with tight thresholds (bootstrap)
    for (int it = 0; it <= 16; ++it) {
        const int ct = (it == 16) ? 0 : it;
        const bool collect = (it > 0);
        const int j0 = j0c + ct * 128;

        float eev[4];
#pragma unroll
        for (int fj = 0; fj < 4; ++fj) eev[fj] = ee[j0 + wc + fj * 16 + l15];

        f32x4 acc[4][4];
#pragma unroll
        for (int fi = 0; fi < 4; ++fi)
#pragma unroll
            for (int fj = 0; fj < 4; ++fj)
#pragma unroll
                for (int r = 0; r < 4; ++r) acc[fi][fj][r] = 0.0f;

#pragma unroll
        for (int kc = 0; kc < 8; ++kc) {
            // issue next buffer's loads BEFORE consuming current (stay in flight)
            int nit = it, nkc = kc + 1;
            if (nkc == 8) { nkc = 0; nit = it + 1; }
            const int nct = (nit >= 16) ? 0 : nit;
            if (kc & 1) {
                LOADB(bufA, nct, nkc);
#pragma unroll
                for (int fi = 0; fi < 4; ++fi)
#pragma unroll
                    for (int fj = 0; fj < 4; ++fj)
                        acc[fi][fj] = __builtin_amdgcn_mfma_f32_16x16x32_bf16(
                            af[fi][kc], bufB[fj], acc[fi][fj], 0, 0, 0);
            } else {
                LOADB(bufB, nct, nkc);
#pragma unroll
                for (int fi = 0; fi < 4; ++fi)
#pragma unroll
                    for (int fj = 0; fj < 4; ++fj)
                        acc[fi][fj] = __builtin_amdgcn_mfma_f32_16x16x32_bf16(
                            af[fi][kc], bufA[fj], acc[fi][fj], 0, 0, 0);
            }
        }

        // ---- any-skip epilogue: v = ee - 2*dot ----
#pragma unroll
        for (int fi = 0; fi < 4; ++fi) {
#pragma unroll
            for (int r = 0; r < 4; ++r) {
                float vv[4];
#pragma unroll
                for (int fj = 0; fj < 4; ++fj) vv[fj] = fmaf(-2.0f, acc[fi][fj][r], eev[fj]);
                const float lmin = fminf(fminf(vv[0], vv[1]), fminf(vv[2], vv[3]));
                const int rl = wr + fi * 16 + quad * 4 + r;
                const u32 pre = rowthr[rl];                 // history BEFORE own update
                const float thr = funmap(pre) + CMARG;      // finite (THR_INIT sentinel)
                // skip-safe: no lane <= thr => no collect AND wave-min > pre (atomic no-op)
                if (__any(lmin <= thr)) {
                    float m = lmin;
                    m = fminf(m, __shfl_xor(m, 1, 16));
                    m = fminf(m, __shfl_xor(m, 2, 16));
                    m = fminf(m, __shfl_xor(m, 4, 16));
                    m = fminf(m, __shfl_xor(m, 8, 16));
                    if (l15 == 0) atomicMin(&rowthr[rl], fmap(m));
                    if (collect) {
                        // pre >= global row min => thr complete for the np winner
#pragma unroll
                        for (int fj = 0; fj < 4; ++fj) {
                            if (vv[fj] <= thr) {
                                const int rg = n0 + rl;
                                u32 p = atomicAdd(&cnt[rg], 1u);
                                if (p < SLOTS)
                                    cand[(size_t)rg * SLOTS + p] = (u16)(j0 + wc + fj * 16 + l15);
                            }
                        }
                    }
                }
            }
        }
        // every-tile cross-chunk threshold exchange (monotone-safe, no barrier)
        if (t < 128) {
            const u32 lv = rowthr[t];
            const u32 old = atomicMin(&gmin[n0 + t], lv);
            if (old < lv) atomicMin(&rowthr[t], old);
        }
    }
#undef LOADB
}

// numpy-bitwise rescore of ALL collected candidates (winner provably in set)
__global__ __launch_bounds__(64)
void k_rescore(const float* __restrict__ z, const float* __restrict__ E,
               const float* __restrict__ zz, const float* __restrict__ ee,
               const u32* __restrict__ cnt, const u16* __restrict__ cand,
               float* __restrict__ out_idx) {
    const int q = blockIdx.x;
    const int t = threadIdx.x;
    const int b = q >> 10, hw = q & 1023;
    const u32 n = min(cnt[q], (u32)SLOTS);

    u64 best = 0xFFFFFFFFFFFFFFFFULL;
#pragma unroll
    for (int s = 0; s < 2; ++s) {
        const u32 slot = (u32)t + s * 64;
        if (slot < n) {
            const int j = (int)cand[(size_t)q * SLOTS + slot] & (NE - 1);   // OOB-proof
            const float ze = np_einsum_dot(z + (size_t)b * BSTR + hw, CSTR, E + (size_t)j * DIMK);
            const float t1 = __fadd_rn(zz[q], ee[j]);
            const float d  = __fsub_rn(t1, __fmul_rn(2.0f, ze));
            u64 key = ((u64)fmap(d) << 32) | (u32)j;   // ties -> lowest j
            if (key < best) best = key;
        }
    }
#pragma unroll
    for (int off = 1; off < 64; off <<= 1) {
        u64 o = __shfl_xor(best, off, 64);
        if (o < best) best = o;
    }
    if (t == 0) out_idx[q] = (float)((int)(best & 0xFFFFFFFFULL) & (NE - 1));
}

// gather + transpose + loss; 256 blocks (32 q-groups x 8 c-groups)
__global__ __launch_bounds__(256)
void k_finalize(const float* __restrict__ z, const float* __restrict__ E,
                const float* __restrict__ out_idx,
                float* __restrict__ out0, float* __restrict__ acc) {
    __shared__ float T[256 * 33];
    __shared__ float red[256];
    const int t  = threadIdx.x;
    const int qg = blockIdx.x >> 3;
    const int ch = blockIdx.x & 7;
    const int q0 = qg * 256;
    const int c0 = ch * 32;
    const int b  = q0 >> 10, hw0 = q0 & 1023;
    const int idx = ((int)out_idx[q0 + t]) & (NE - 1);
    const float* er = E + (size_t)idx * DIMK + c0;
#pragma unroll
    for (int i = 0; i < 8; ++i) {
        float4 f = *(const float4*)(er + i * 4);
        T[t * 33 + i * 4 + 0] = f.x;
        T[t * 33 + i * 4 + 1] = f.y;
        T[t * 33 + i * 4 + 2] = f.z;
        T[t * 33 + i * 4 + 3] = f.w;
    }
    __syncthreads();
    float ls = 0.0f;
#pragma unroll 4
    for (int cc = 0; cc < 32; ++cc) {
        // output (c0+cc, hw0+t) gets row q=hw0+t's embedding value, from T[t][cc]
        const float ev = T[t * 33 + cc];
        const size_t o = (size_t)b * BSTR + (size_t)(c0 + cc) * CSTR + hw0 + t;
        const float d = ev - z[o];
        ls = fmaf(d, d, ls);
        out0[o] = ev;
    }
    red[t] = ls;
    __syncthreads();
    for (int s = 128; s > 0; s >>= 1) {
        if (t < s) red[t] += red[t + s];
        __syncthreads();
    }
    if (t == 0) atomicAdd(acc, red[0]);
}

__global__ void k_loss(const float* __restrict__ acc, float* __restrict__ out_loss) {
    *out_loss = 1.25f * (*acc) * (1.0f / 2097152.0f);
}

extern "C" void kernel_launch(void* const* d_in, const int* in_sizes, int n_in,
                              void* d_out, int out_size, void* d_ws, size_t ws_size,
                              hipStream_t stream) {
    const float* z = (const float*)d_in[0];   // [8,256,32,32] fp32
    const float* E = (const float*)d_in[1];   // [16384,256] fp32

    float* out0     = (float*)d_out;
    float* out_loss = (float*)d_out + 2097152;
    float* out_idx  = (float*)d_out + 2097153;

    float*    acc  = (float*)d_ws;
    float*    ee   = (float*)((char*)d_ws + WS_EE);
    float*    zz   = (float*)((char*)d_ws + WS_ZZ);
    u32*      gmin = (u32*)  ((char*)d_ws + WS_GMIN);
    u32*      cnt  = (u32*)  ((char*)d_ws + WS_CNT);
    u16*      cand = (u16*)  ((char*)d_ws + WS_CAND);
    ushort_t* Ep   = (ushort_t*)((char*)d_ws + WS_EP);

    k_prep<<<1536, 256, 0, stream>>>(z, E, ee, zz, gmin, cnt, acc, Ep);
    k_filter<<<512, 256, 0, stream>>>(z, Ep, ee, gmin, cnt, cand);
    k_rescore<<<NQ, 64, 0, stream>>>(z, E, zz, ee, cnt, cand, out_idx);
    k_finalize<<<256, 256, 0, stream>>>(z, E, out_idx, out0, acc);
    k_loss<<<1, 1, 0, stream>>>(acc, out_loss);
}